// Round 1
// baseline (201.303 us; speedup 1.0000x reference)
//
#include <hip/hip_runtime.h>
#include <stdint.h>

typedef unsigned int u32;
typedef unsigned short u16;
typedef float f32x4 __attribute__((ext_vector_type(4)));
typedef short s16x8 __attribute__((ext_vector_type(8)));

#define NB   8
#define CIN  256
#define HH   64
#define WW   64
#define HW   4096
#define COUT 256
#define KKT  9
#define KTOT 2304   // KKT*CIN, k ordered as (kk, c)

__device__ __forceinline__ u32 bf16_rne(float f) {
  u32 u = __float_as_uint(f);
  return (u + 0x7fffu + ((u >> 16) & 1u)) >> 16;
}
__device__ __forceinline__ float blo(u32 u) { return __uint_as_float(u << 16); }
__device__ __forceinline__ float bhi(u32 u) { return __uint_as_float(u & 0xffff0000u); }
// pack 2 fp32 -> bf16 pair (round-half-up; error << threshold)
__device__ __forceinline__ u32 pk2(float lo, float hi) {
  return ((__float_as_uint(hi) + 0x8000u) & 0xffff0000u) |
         ((__float_as_uint(lo) + 0x8000u) >> 16);
}

// ---- prep_w: W2[co][kk][c] (bf16) = weight[co][c][kk] ----
__global__ __launch_bounds__(256) void prep_w(const float* __restrict__ w,
                                              u16* __restrict__ W2) {
  int t = blockIdx.x * 256 + threadIdx.x;   // 589824 total
  int c = t & 255;
  int rest = t >> 8;                         // co*9 + kk
  int kk = rest % 9;
  int co = rest / 9;
  float v = w[((size_t)co * CIN + c) * 9 + kk];
  W2[t] = (u16)bf16_rne(v);
}

// ---- prep_x: xT[n][hw][c] bf16 (u32-pair packed) from x[n][c][hw] fp32 ----
__global__ __launch_bounds__(256) void prep_x(const float* __restrict__ x,
                                              u32* __restrict__ xT) {
  __shared__ u32 tile[64][130];   // [hw_local][c_pair], stride 130 -> 2-way banks (free)
  int b = blockIdx.x;             // 512 blocks: n = b>>6, hw0 = (b&63)*64
  int n = b >> 6;
  int hw0 = (b & 63) << 6;
  int t = threadIdx.x;
  int hw = t & 63;
  const float* xb = x + (size_t)n * CIN * HW + hw0 + hw;
  int cbase = (t >> 6) * 2;       // 0,2,4,6
  for (int citer = 0; citer < 32; ++citer) {
    int c = (citer << 3) + cbase;
    float v0 = xb[(size_t)c * HW];
    float v1 = xb[(size_t)(c + 1) * HW];
    tile[hw][c >> 1] = bf16_rne(v0) | (bf16_rne(v1) << 16);
  }
  __syncthreads();
  u32* outp = xT + ((size_t)(n * HW + hw0)) * 128;   // 128 u32 per position
  int cp = t & 127;
  int hb = t >> 7;                // 0..1
  for (int it = 0; it < 32; ++it) {
    int hwl = (it << 1) + hb;
    outp[(size_t)hwl * 128 + cp] = tile[hwl][cp];
  }
}

// ---- main fused kernel: one block per (ho, n); 256 Cout x 64 Wo tile ----
__global__ __launch_bounds__(256) void dcn_main(
    const float* __restrict__ offset, const float* __restrict__ mask,
    const float* __restrict__ bias, const u16* __restrict__ xT,
    const u16* __restrict__ W2, float* __restrict__ out) {
  __shared__ u16 As[256 * 32];    // [co][k-chunk 32], chunk-XOR-swizzled, 16KB
  __shared__ u16 Bs[64 * 40];     // [p][k-chunk 32], stride 40 el (80B, 16B-aligned)
  __shared__ float4 swl[576];     // per (kk,p): 4 corner weights (mask+validity folded)
  __shared__ int4 sol[576];       // per (kk,p): 4 corner byte offsets into xT row space

  int ho = blockIdx.x;
  int n  = blockIdx.y;
  int t = threadIdx.x;
  int lane = t & 63;
  int w = t >> 6;                  // wave id 0..3

  // 1) precompute sample info: 9 taps x 64 pixels
  for (int i = t; i < 576; i += 256) {
    int kk = i >> 6, p = i & 63;
    int ky = kk / 3, kx = kk - ky * 3;
    int sp = (ho << 6) + p;
    float dy = offset[(((size_t)n * 18 + kk * 2 + 0) << 12) + sp];
    float dx = offset[(((size_t)n * 18 + kk * 2 + 1) << 12) + sp];
    float m  = mask  [(((size_t)n * 9  + kk) << 12) + sp];
    float ys = (float)(ky + ho - 1) + dy;
    float xs = (float)(kx + p  - 1) + dx;
    float y0f = floorf(ys), x0f = floorf(xs);
    float fy = ys - y0f, fx = xs - x0f;
    int y0 = (int)y0f, x0 = (int)x0f;
    int y1 = y0 + 1, x1 = x0 + 1;
    float vy0 = (y0 >= 0 && y0 < HH) ? 1.f : 0.f;
    float vy1 = (y1 >= 0 && y1 < HH) ? 1.f : 0.f;
    float vx0 = (x0 >= 0 && x0 < WW) ? 1.f : 0.f;
    float vx1 = (x1 >= 0 && x1 < WW) ? 1.f : 0.f;
    float4 wv;
    wv.x = (1.f - fy) * (1.f - fx) * m * vy0 * vx0;
    wv.y = (1.f - fy) * fx * m * vy0 * vx1;
    wv.z = fy * (1.f - fx) * m * vy1 * vx0;
    wv.w = fy * fx * m * vy1 * vx1;
    int iy0 = min(max(y0, 0), HH - 1), iy1 = min(max(y1, 0), HH - 1);
    int ix0 = min(max(x0, 0), WW - 1), ix1 = min(max(x1, 0), WW - 1);
    int4 ov;
    ov.x = ((iy0 << 6) + ix0) << 9;   // *512 bytes (256 bf16 channels per position)
    ov.y = ((iy0 << 6) + ix1) << 9;
    ov.z = ((iy1 << 6) + ix0) << 9;
    ov.w = ((iy1 << 6) + ix1) << 9;
    swl[i] = wv;
    sol[i] = ov;
  }
  __syncthreads();

  f32x4 acc[4][4];
#pragma unroll
  for (int a = 0; a < 4; ++a)
#pragma unroll
    for (int b2 = 0; b2 < 4; ++b2) acc[a][b2] = {0.f, 0.f, 0.f, 0.f};

  const char* xTn = (const char*)xT + ((size_t)n * HW << 9);
  int ml = lane & 15, q = lane >> 4;
  int p_s = lane;                     // sampling pixel for this thread

  for (int kk = 0; kk < 9; ++kk) {
    const float4 wv = swl[(kk << 6) + p_s];
    const int4 ov = sol[(kk << 6) + p_s];
#pragma unroll 1
    for (int cc = 0; cc < 8; ++cc) {
      // -- stage A tile async (global_load_lds, 16B/lane, XOR chunk swizzle) --
#pragma unroll
      for (int j = 0; j < 4; ++j) {
        int seg = (w << 2) + j;                 // 0..15, 16 rows each
        int row = (seg << 4) + (lane >> 2);     // co
        int gch = (lane & 3) ^ (row & 3);       // swizzled global chunk
        const u16* g = W2 + (size_t)row * KTOT + (kk << 8) + (cc << 5) + (gch << 3);
        __builtin_amdgcn_global_load_lds(
            (const __attribute__((address_space(1))) u32*)g,
            (__attribute__((address_space(3))) u32*)&As[seg << 9], 16, 0, 0);
      }
      // -- build B tile: bilinear sample 8 channels for (kk, p_s) --
      {
        const char* bch = xTn + (((cc << 5) + (w << 3)) << 1);  // channel base
        float s0=0.f,s1=0.f,s2=0.f,s3=0.f,s4=0.f,s5=0.f,s6=0.f,s7=0.f;
        {
          uint4 qv = *(const uint4*)(bch + ov.x); float wt = wv.x;
          s0 += wt*blo(qv.x); s1 += wt*bhi(qv.x); s2 += wt*blo(qv.y); s3 += wt*bhi(qv.y);
          s4 += wt*blo(qv.z); s5 += wt*bhi(qv.z); s6 += wt*blo(qv.w); s7 += wt*bhi(qv.w);
        }
        {
          uint4 qv = *(const uint4*)(bch + ov.y); float wt = wv.y;
          s0 += wt*blo(qv.x); s1 += wt*bhi(qv.x); s2 += wt*blo(qv.y); s3 += wt*bhi(qv.y);
          s4 += wt*blo(qv.z); s5 += wt*bhi(qv.z); s6 += wt*blo(qv.w); s7 += wt*bhi(qv.w);
        }
        {
          uint4 qv = *(const uint4*)(bch + ov.z); float wt = wv.z;
          s0 += wt*blo(qv.x); s1 += wt*bhi(qv.x); s2 += wt*blo(qv.y); s3 += wt*bhi(qv.y);
          s4 += wt*blo(qv.z); s5 += wt*bhi(qv.z); s6 += wt*blo(qv.w); s7 += wt*bhi(qv.w);
        }
        {
          uint4 qv = *(const uint4*)(bch + ov.w); float wt = wv.w;
          s0 += wt*blo(qv.x); s1 += wt*bhi(qv.x); s2 += wt*blo(qv.y); s3 += wt*bhi(qv.y);
          s4 += wt*blo(qv.z); s5 += wt*bhi(qv.z); s6 += wt*blo(qv.w); s7 += wt*bhi(qv.w);
        }
        uint4 pkd;
        pkd.x = pk2(s0, s1); pkd.y = pk2(s2, s3);
        pkd.z = pk2(s4, s5); pkd.w = pk2(s6, s7);
        *(uint4*)((char*)Bs + p_s * 80 + (w << 4)) = pkd;
      }
      __syncthreads();   // drains global_load_lds (vmcnt) + Bs writes
      // -- MFMA: wave w owns co [w*64, w*64+64) x all 64 pixels --
      s16x8 af[4], bf[4];
#pragma unroll
      for (int mt = 0; mt < 4; ++mt) {
        int co = (w << 6) + (mt << 4) + ml;
        int ch = q ^ (co & 3);                  // undo staging swizzle
        af[mt] = *(const s16x8*)&As[(co << 5) + (ch << 3)];
      }
#pragma unroll
      for (int nt = 0; nt < 4; ++nt) {
        bf[nt] = *(const s16x8*)((const char*)Bs + ((nt << 4) + ml) * 80 + (q << 4));
      }
#pragma unroll
      for (int mt = 0; mt < 4; ++mt)
#pragma unroll
        for (int nt = 0; nt < 4; ++nt)
          acc[mt][nt] = __builtin_amdgcn_mfma_f32_16x16x32_bf16(af[mt], bf[nt],
                                                                acc[mt][nt], 0, 0, 0);
      __syncthreads();   // protect As/Bs before next chunk's writes
    }
  }

  // epilogue: D row = q*4+reg, col = ml (m91-verified layout), + bias
  size_t obase = ((size_t)n * COUT) * HW + ((size_t)ho << 6);
#pragma unroll
  for (int mt = 0; mt < 4; ++mt) {
#pragma unroll
    for (int r = 0; r < 4; ++r) {
      int co = (w << 6) + (mt << 4) + (q << 2) + r;
      float bv = bias[co];
#pragma unroll
      for (int nt = 0; nt < 4; ++nt) {
        int wo = (nt << 4) + ml;
        out[obase + (size_t)co * HW + wo] = acc[mt][nt][r] + bv;
      }
    }
  }
}

extern "C" void kernel_launch(void* const* d_in, const int* in_sizes, int n_in,
                              void* d_out, int out_size, void* d_ws, size_t ws_size,
                              hipStream_t stream) {
  const float* x      = (const float*)d_in[0];
  const float* offset = (const float*)d_in[1];
  const float* mask   = (const float*)d_in[2];
  const float* weight = (const float*)d_in[3];
  const float* bias   = (const float*)d_in[4];
  float* out = (float*)d_out;

  u16* xT = (u16*)d_ws;                                      // 16 MB
  u16* W2 = (u16*)((char*)d_ws + (size_t)NB * HW * CIN * 2); // +1.18 MB

  prep_x<<<512, 256, 0, stream>>>(x, (u32*)xT);
  prep_w<<<2304, 256, 0, stream>>>(weight, W2);
  dim3 g(64, 8);
  dcn_main<<<g, 256, 0, stream>>>(offset, mask, bias, xT, W2, out);
}

// Round 2
// 183.753 us; speedup vs baseline: 1.0955x; 1.0955x over previous
//
#include <hip/hip_runtime.h>
#include <stdint.h>

typedef unsigned int u32;
typedef unsigned short u16;
typedef float f32x4 __attribute__((ext_vector_type(4)));
typedef short s16x8 __attribute__((ext_vector_type(8)));

#define NB   8
#define CIN  256
#define HH   64
#define WW   64
#define HW   4096
#define COUT 256

__device__ __forceinline__ u32 bf16_rne(float f) {
  u32 u = __float_as_uint(f);
  return (u + 0x7fffu + ((u >> 16) & 1u)) >> 16;
}
__device__ __forceinline__ float blo(u32 u) { return __uint_as_float(u << 16); }
__device__ __forceinline__ float bhi(u32 u) { return __uint_as_float(u & 0xffff0000u); }
__device__ __forceinline__ u32 pk2(float lo, float hi) {
  return ((__float_as_uint(hi) + 0x8000u) & 0xffff0000u) |
         ((__float_as_uint(lo) + 0x8000u) >> 16);
}

// ---- prep_w: W2f in MFMA A-fragment order ----
// frag idx = ((kk*8+cc)*16 + (w*4+mt))*64 + lane, 8 bf16 each.
// co = (tile>>2)*64 + (tile&3)*16 + (lane&15); c = cc*32 + (lane>>4)*8 + j.
__global__ __launch_bounds__(256) void prep_w(const float* __restrict__ w,
                                              u16* __restrict__ W2f) {
  int t = blockIdx.x * 256 + threadIdx.x;   // 73728 total (288 blocks)
  int lane = t & 63;
  int tile = (t >> 6) & 15;
  int cc = (t >> 10) & 7;
  int kk = t >> 13;                          // 0..8
  int co = ((tile >> 2) << 6) + ((tile & 3) << 4) + (lane & 15);
  int c0 = (cc << 5) + ((lane >> 4) << 3);
  u32 pk[4];
#pragma unroll
  for (int jj = 0; jj < 4; ++jj) {
    float v0 = w[((size_t)co * CIN + c0 + 2 * jj) * 9 + kk];
    float v1 = w[((size_t)co * CIN + c0 + 2 * jj + 1) * 9 + kk];
    pk[jj] = bf16_rne(v0) | (bf16_rne(v1) << 16);
  }
  *(uint4*)(W2f + (size_t)t * 8) = *(uint4*)pk;
}

// ---- prep_x: xT[n][hw][c] bf16 from x[n][c][hw] fp32 ----
__global__ __launch_bounds__(256) void prep_x(const float* __restrict__ x,
                                              u32* __restrict__ xT) {
  __shared__ u32 tile[64][129];   // 129: (hw+cp)%32 -> 2-way max (free)
  int b = blockIdx.x;
  int n = b >> 6;
  int hw0 = (b & 63) << 6;
  int t = threadIdx.x;
  int hw = t & 63;
  const float* xb = x + (size_t)n * CIN * HW + hw0 + hw;
  int cbase = (t >> 6) * 2;
  for (int citer = 0; citer < 32; ++citer) {
    int c = (citer << 3) + cbase;
    float v0 = xb[(size_t)c * HW];
    float v1 = xb[(size_t)(c + 1) * HW];
    tile[hw][c >> 1] = bf16_rne(v0) | (bf16_rne(v1) << 16);
  }
  __syncthreads();
  u32* outp = xT + ((size_t)(n * HW + hw0)) * 128;
  int cp = t & 127;
  int hb = t >> 7;
  for (int it = 0; it < 32; ++it) {
    int hwl = (it << 1) + hb;
    outp[(size_t)hwl * 128 + cp] = tile[hwl][cp];
  }
}

// ---- main fused kernel: one block per (n, ho); 256 Cout x 64 Wo ----
#define BSTRIDE 264   // u16 per Bs row (256 + 8 pad; 528B, 16B-aligned)

__global__ __launch_bounds__(256) void dcn_main(
    const float* __restrict__ offset, const float* __restrict__ mask,
    const float* __restrict__ bias, const u16* __restrict__ xT,
    const u16* __restrict__ W2f, float* __restrict__ out) {
  __shared__ __align__(16) u16 Bs[64 * BSTRIDE];  // full-tap B tile: 64px x 256ch
  __shared__ __align__(16) float4 swl[576];       // (kk,p): 4 corner wts (mask folded)
  __shared__ __align__(16) int4 sol[576];         // (kk,p): 4 corner byte offsets

  int bid = blockIdx.x;      // 512 blocks
  int n = bid & 7;           // XCD swizzle: XCD k serves only n==k -> 2MB slice in L2
  int ho = bid >> 3;
  int t = threadIdx.x;
  int lane = t & 63;
  int w = t >> 6;

  // 1) sample precompute: 9 taps x 64 px
  for (int i = t; i < 576; i += 256) {
    int kk = i >> 6, p = i & 63;
    int ky = kk / 3, kx = kk - ky * 3;
    int sp = (ho << 6) + p;
    float dy = offset[(((size_t)n * 18 + kk * 2 + 0) << 12) + sp];
    float dx = offset[(((size_t)n * 18 + kk * 2 + 1) << 12) + sp];
    float m  = mask  [(((size_t)n * 9  + kk) << 12) + sp];
    float ys = (float)(ky + ho - 1) + dy;
    float xs = (float)(kx + p  - 1) + dx;
    float y0f = floorf(ys), x0f = floorf(xs);
    float fy = ys - y0f, fx = xs - x0f;
    int y0 = (int)y0f, x0 = (int)x0f;
    int y1 = y0 + 1, x1 = x0 + 1;
    float vy0 = (y0 >= 0 && y0 < HH) ? 1.f : 0.f;
    float vy1 = (y1 >= 0 && y1 < HH) ? 1.f : 0.f;
    float vx0 = (x0 >= 0 && x0 < WW) ? 1.f : 0.f;
    float vx1 = (x1 >= 0 && x1 < WW) ? 1.f : 0.f;
    float4 wv;
    wv.x = (1.f - fy) * (1.f - fx) * m * vy0 * vx0;
    wv.y = (1.f - fy) * fx * m * vy0 * vx1;
    wv.z = fy * (1.f - fx) * m * vy1 * vx0;
    wv.w = fy * fx * m * vy1 * vx1;
    int iy0 = min(max(y0, 0), HH - 1), iy1 = min(max(y1, 0), HH - 1);
    int ix0 = min(max(x0, 0), WW - 1), ix1 = min(max(x1, 0), WW - 1);
    int4 ov;
    ov.x = ((iy0 << 6) + ix0) << 9;
    ov.y = ((iy0 << 6) + ix1) << 9;
    ov.z = ((iy1 << 6) + ix0) << 9;
    ov.w = ((iy1 << 6) + ix1) << 9;
    swl[i] = wv;
    sol[i] = ov;
  }
  __syncthreads();

  f32x4 acc[4][4];
#pragma unroll
  for (int a = 0; a < 4; ++a)
#pragma unroll
    for (int b2 = 0; b2 < 4; ++b2) acc[a][b2] = {0.f, 0.f, 0.f, 0.f};

  const char* xTn = (const char*)xT + ((size_t)n * HW << 9);
  int ml = lane & 15, q = lane >> 4;
  int hwid = t >> 5;     // half-wave id 0..7
  int l32 = t & 31;

  for (int kk = 0; kk < 9; ++kk) {
    // -- build full-tap Bs: half-wave covers one pixel's 256 channels --
    // per corner: 32 lanes x 16B = 512B contiguous (coalesced)
#pragma unroll 2
    for (int i = 0; i < 8; ++i) {
      int px = (i << 3) + hwid;
      const float4 wv = swl[(kk << 6) + px];   // LDS broadcast
      const int4 ov = sol[(kk << 6) + px];
      const char* bch = xTn + (l32 << 4);
      float s0=0.f,s1=0.f,s2=0.f,s3=0.f,s4=0.f,s5=0.f,s6=0.f,s7=0.f;
      {
        uint4 qv = *(const uint4*)(bch + ov.x); float wt = wv.x;
        s0 += wt*blo(qv.x); s1 += wt*bhi(qv.x); s2 += wt*blo(qv.y); s3 += wt*bhi(qv.y);
        s4 += wt*blo(qv.z); s5 += wt*bhi(qv.z); s6 += wt*blo(qv.w); s7 += wt*bhi(qv.w);
      }
      {
        uint4 qv = *(const uint4*)(bch + ov.y); float wt = wv.y;
        s0 += wt*blo(qv.x); s1 += wt*bhi(qv.x); s2 += wt*blo(qv.y); s3 += wt*bhi(qv.y);
        s4 += wt*blo(qv.z); s5 += wt*bhi(qv.z); s6 += wt*blo(qv.w); s7 += wt*bhi(qv.w);
      }
      {
        uint4 qv = *(const uint4*)(bch + ov.z); float wt = wv.z;
        s0 += wt*blo(qv.x); s1 += wt*bhi(qv.x); s2 += wt*blo(qv.y); s3 += wt*bhi(qv.y);
        s4 += wt*blo(qv.z); s5 += wt*bhi(qv.z); s6 += wt*blo(qv.w); s7 += wt*bhi(qv.w);
      }
      {
        uint4 qv = *(const uint4*)(bch + ov.w); float wt = wv.w;
        s0 += wt*blo(qv.x); s1 += wt*bhi(qv.x); s2 += wt*blo(qv.y); s3 += wt*bhi(qv.y);
        s4 += wt*blo(qv.z); s5 += wt*bhi(qv.z); s6 += wt*blo(qv.w); s7 += wt*bhi(qv.w);
      }
      uint4 pkd;
      pkd.x = pk2(s0, s1); pkd.y = pk2(s2, s3);
      pkd.z = pk2(s4, s5); pkd.w = pk2(s6, s7);
      *(uint4*)((char*)Bs + px * (BSTRIDE * 2) + (l32 << 4)) = pkd;
    }
    __syncthreads();

    // -- MFMA over 8 chunks of K=32; NO barriers inside --
    // A-fragments straight from L2 (fragment-ordered W2f, fully coalesced)
#pragma unroll 2
    for (int cc = 0; cc < 8; ++cc) {
      s16x8 af[4], bf[4];
      const u16* abase = W2f + ((((size_t)(kk * 8 + cc) << 4) + (w << 2)) << 6 << 3);
#pragma unroll
      for (int mt = 0; mt < 4; ++mt)
        af[mt] = *(const s16x8*)(abase + (((mt << 6) + lane) << 3));
#pragma unroll
      for (int nt = 0; nt < 4; ++nt)
        bf[nt] = *(const s16x8*)((const char*)Bs +
                 ((nt << 4) + ml) * (BSTRIDE * 2) + (cc << 6) + (q << 4));
#pragma unroll
      for (int mt = 0; mt < 4; ++mt)
#pragma unroll
        for (int nt = 0; nt < 4; ++nt)
          acc[mt][nt] = __builtin_amdgcn_mfma_f32_16x16x32_bf16(af[mt], bf[nt],
                                                                acc[mt][nt], 0, 0, 0);
    }
    __syncthreads();   // protect Bs before next kk's rebuild
  }

  // epilogue: D row = q*4+r, col = ml (m91-verified), + bias
  size_t obase = ((size_t)n * COUT) * HW + ((size_t)ho << 6);
#pragma unroll
  for (int mt = 0; mt < 4; ++mt) {
#pragma unroll
    for (int r = 0; r < 4; ++r) {
      int co = (w << 6) + (mt << 4) + (q << 2) + r;
      float bv = bias[co];
#pragma unroll
      for (int nt = 0; nt < 4; ++nt) {
        int wo = (nt << 4) + ml;
        out[obase + (size_t)co * HW + wo] = acc[mt][nt][r] + bv;
      }
    }
  }
}

extern "C" void kernel_launch(void* const* d_in, const int* in_sizes, int n_in,
                              void* d_out, int out_size, void* d_ws, size_t ws_size,
                              hipStream_t stream) {
  const float* x      = (const float*)d_in[0];
  const float* offset = (const float*)d_in[1];
  const float* mask   = (const float*)d_in[2];
  const float* weight = (const float*)d_in[3];
  const float* bias   = (const float*)d_in[4];
  float* out = (float*)d_out;

  u16* xT  = (u16*)d_ws;                                      // 16 MB
  u16* W2f = (u16*)((char*)d_ws + (size_t)NB * HW * CIN * 2); // +1.18 MB

  prep_x<<<512, 256, 0, stream>>>(x, (u32*)xT);
  prep_w<<<288, 256, 0, stream>>>(weight, W2f);
  dcn_main<<<512, 256, 0, stream>>>(offset, mask, bias, xT, W2f, out);
}

// Round 3
// 153.261 us; speedup vs baseline: 1.3135x; 1.1990x over previous
//
#include <hip/hip_runtime.h>
#include <stdint.h>

typedef unsigned int u32;
typedef unsigned short u16;
typedef float f32x4 __attribute__((ext_vector_type(4)));
typedef short s16x8 __attribute__((ext_vector_type(8)));

#define NB   8
#define CIN  256
#define HH   64
#define WW   64
#define HW   4096
#define COUT 256

__device__ __forceinline__ u32 bf16_rne(float f) {
  u32 u = __float_as_uint(f);
  return (u + 0x7fffu + ((u >> 16) & 1u)) >> 16;
}
__device__ __forceinline__ float blo(u32 u) { return __uint_as_float(u << 16); }
__device__ __forceinline__ float bhi(u32 u) { return __uint_as_float(u & 0xffff0000u); }
__device__ __forceinline__ u32 pk2(float lo, float hi) {
  return ((__float_as_uint(hi) + 0x8000u) & 0xffff0000u) |
         ((__float_as_uint(lo) + 0x8000u) >> 16);
}

// ---- prep_w: W2f in MFMA A-fragment order ----
// frag idx = ((kk*8+cc)*16 + tile)*64 + lane, 8 bf16 each.
// co = (tile>>2)*64 + (tile&3)*16 + (lane&15); c = cc*32 + (lane>>4)*8 + j.
__global__ __launch_bounds__(256) void prep_w(const float* __restrict__ w,
                                              u16* __restrict__ W2f) {
  int t = blockIdx.x * 256 + threadIdx.x;   // 73728 total (288 blocks)
  int lane = t & 63;
  int tile = (t >> 6) & 15;
  int cc = (t >> 10) & 7;
  int kk = t >> 13;                          // 0..8
  int co = ((tile >> 2) << 6) + ((tile & 3) << 4) + (lane & 15);
  int c0 = (cc << 5) + ((lane >> 4) << 3);
  u32 pk[4];
#pragma unroll
  for (int jj = 0; jj < 4; ++jj) {
    float v0 = w[((size_t)co * CIN + c0 + 2 * jj) * 9 + kk];
    float v1 = w[((size_t)co * CIN + c0 + 2 * jj + 1) * 9 + kk];
    pk[jj] = bf16_rne(v0) | (bf16_rne(v1) << 16);
  }
  *(uint4*)(W2f + (size_t)t * 8) = *(uint4*)pk;
}

// ---- prep_x: xT[n][hw][c] bf16 from x[n][c][hw] fp32 ----
__global__ __launch_bounds__(256) void prep_x(const float* __restrict__ x,
                                              u32* __restrict__ xT) {
  __shared__ u32 tile[64][129];
  int b = blockIdx.x;
  int n = b >> 6;
  int hw0 = (b & 63) << 6;
  int t = threadIdx.x;
  int hw = t & 63;
  const float* xb = x + (size_t)n * CIN * HW + hw0 + hw;
  int cbase = (t >> 6) * 2;
  for (int citer = 0; citer < 32; ++citer) {
    int c = (citer << 3) + cbase;
    float v0 = xb[(size_t)c * HW];
    float v1 = xb[(size_t)(c + 1) * HW];
    tile[hw][c >> 1] = bf16_rne(v0) | (bf16_rne(v1) << 16);
  }
  __syncthreads();
  u32* outp = xT + ((size_t)(n * HW + hw0)) * 128;
  int cp = t & 127;
  int hb = t >> 7;
  for (int it = 0; it < 32; ++it) {
    int hwl = (it << 1) + hb;
    outp[(size_t)hwl * 128 + cp] = tile[hwl][cp];
  }
}

// ---- main fused kernel: 512 threads (8 waves), one block per (n, ho) ----
// 2 blocks/CU co-resident -> 16 waves/CU (was 8): latency hiding is the point.
#define BSTRIDE 264   // u16 per Bs row (256 + 8 pad; 528B, 16B-aligned)

__global__ __launch_bounds__(512, 4) void dcn_main(
    const float* __restrict__ offset, const float* __restrict__ mask,
    const float* __restrict__ bias, const u16* __restrict__ xT,
    const u16* __restrict__ W2f, float* __restrict__ out) {
  __shared__ __align__(16) u16 Bs[64 * BSTRIDE];  // full-tap B tile: 64px x 256ch
  __shared__ __align__(16) float4 swl[576];       // (kk,p): 4 corner wts (mask folded)
  __shared__ __align__(16) int4 sol[576];         // (kk,p): 4 corner byte offsets

  int bid = blockIdx.x;      // 512 blocks
  int n = bid & 7;           // XCD swizzle: XCD k serves n==k -> 2MB xT slice in L2
  int ho = bid >> 3;
  int t = threadIdx.x;
  int lane = t & 63;
  int w = t >> 6;            // wave 0..7

  // 1) sample precompute: 9 taps x 64 px
  for (int i = t; i < 576; i += 512) {
    int kk = i >> 6, p = i & 63;
    int ky = kk / 3, kx = kk - ky * 3;
    int sp = (ho << 6) + p;
    float dy = offset[(((size_t)n * 18 + kk * 2 + 0) << 12) + sp];
    float dx = offset[(((size_t)n * 18 + kk * 2 + 1) << 12) + sp];
    float m  = mask  [(((size_t)n * 9  + kk) << 12) + sp];
    float ys = (float)(ky + ho - 1) + dy;
    float xs = (float)(kx + p  - 1) + dx;
    float y0f = floorf(ys), x0f = floorf(xs);
    float fy = ys - y0f, fx = xs - x0f;
    int y0 = (int)y0f, x0 = (int)x0f;
    int y1 = y0 + 1, x1 = x0 + 1;
    float vy0 = (y0 >= 0 && y0 < HH) ? 1.f : 0.f;
    float vy1 = (y1 >= 0 && y1 < HH) ? 1.f : 0.f;
    float vx0 = (x0 >= 0 && x0 < WW) ? 1.f : 0.f;
    float vx1 = (x1 >= 0 && x1 < WW) ? 1.f : 0.f;
    float4 wv;
    wv.x = (1.f - fy) * (1.f - fx) * m * vy0 * vx0;
    wv.y = (1.f - fy) * fx * m * vy0 * vx1;
    wv.z = fy * (1.f - fx) * m * vy1 * vx0;
    wv.w = fy * fx * m * vy1 * vx1;
    int iy0 = min(max(y0, 0), HH - 1), iy1 = min(max(y1, 0), HH - 1);
    int ix0 = min(max(x0, 0), WW - 1), ix1 = min(max(x1, 0), WW - 1);
    int4 ov;
    ov.x = ((iy0 << 6) + ix0) << 9;
    ov.y = ((iy0 << 6) + ix1) << 9;
    ov.z = ((iy1 << 6) + ix0) << 9;
    ov.w = ((iy1 << 6) + ix1) << 9;
    swl[i] = wv;
    sol[i] = ov;
  }
  __syncthreads();

  f32x4 acc[2][4];
#pragma unroll
  for (int a = 0; a < 2; ++a)
#pragma unroll
    for (int b2 = 0; b2 < 4; ++b2) acc[a][b2] = {0.f, 0.f, 0.f, 0.f};

  const char* xTn = (const char*)xT + ((size_t)n * HW << 9);
  int ml = lane & 15, q = lane >> 4;
  int hwid = t >> 5;     // half-wave id 0..15
  int l32 = t & 31;
  // A-fragment tile base for this wave: co0 = w*32
  int tile0 = ((w >> 1) << 2) + ((w & 1) << 1);   // tile index of mt=0

  for (int kk = 0; kk < 9; ++kk) {
    // -- build full-tap Bs: half-wave covers one pixel's 256 channels --
#pragma unroll 2
    for (int i = 0; i < 4; ++i) {
      int px = (i << 4) + hwid;
      const float4 wv = swl[(kk << 6) + px];
      const int4 ov = sol[(kk << 6) + px];
      const char* bch = xTn + (l32 << 4);
      float s0=0.f,s1=0.f,s2=0.f,s3=0.f,s4=0.f,s5=0.f,s6=0.f,s7=0.f;
      {
        uint4 qv = *(const uint4*)(bch + ov.x); float wt = wv.x;
        s0 += wt*blo(qv.x); s1 += wt*bhi(qv.x); s2 += wt*blo(qv.y); s3 += wt*bhi(qv.y);
        s4 += wt*blo(qv.z); s5 += wt*bhi(qv.z); s6 += wt*blo(qv.w); s7 += wt*bhi(qv.w);
      }
      {
        uint4 qv = *(const uint4*)(bch + ov.y); float wt = wv.y;
        s0 += wt*blo(qv.x); s1 += wt*bhi(qv.x); s2 += wt*blo(qv.y); s3 += wt*bhi(qv.y);
        s4 += wt*blo(qv.z); s5 += wt*bhi(qv.z); s6 += wt*blo(qv.w); s7 += wt*bhi(qv.w);
      }
      {
        uint4 qv = *(const uint4*)(bch + ov.z); float wt = wv.z;
        s0 += wt*blo(qv.x); s1 += wt*bhi(qv.x); s2 += wt*blo(qv.y); s3 += wt*bhi(qv.y);
        s4 += wt*blo(qv.z); s5 += wt*bhi(qv.z); s6 += wt*blo(qv.w); s7 += wt*bhi(qv.w);
      }
      {
        uint4 qv = *(const uint4*)(bch + ov.w); float wt = wv.w;
        s0 += wt*blo(qv.x); s1 += wt*bhi(qv.x); s2 += wt*blo(qv.y); s3 += wt*bhi(qv.y);
        s4 += wt*blo(qv.z); s5 += wt*bhi(qv.z); s6 += wt*blo(qv.w); s7 += wt*bhi(qv.w);
      }
      uint4 pkd;
      pkd.x = pk2(s0, s1); pkd.y = pk2(s2, s3);
      pkd.z = pk2(s4, s5); pkd.w = pk2(s6, s7);
      *(uint4*)((char*)Bs + px * (BSTRIDE * 2) + (l32 << 4)) = pkd;
    }
    __syncthreads();

    // -- MFMA over 8 chunks of K=32; NO barriers inside --
#pragma unroll 2
    for (int cc = 0; cc < 8; ++cc) {
      s16x8 af[2], bf[4];
      const u16* abase = W2f + (((size_t)(kk * 8 + cc) << 4) << 6 << 3);
#pragma unroll
      for (int mt = 0; mt < 2; ++mt)
        af[mt] = *(const s16x8*)(abase + ((((tile0 + mt) << 6) + lane) << 3));
#pragma unroll
      for (int nt = 0; nt < 4; ++nt)
        bf[nt] = *(const s16x8*)((const char*)Bs +
                 ((nt << 4) + ml) * (BSTRIDE * 2) + (cc << 6) + (q << 4));
#pragma unroll
      for (int mt = 0; mt < 2; ++mt)
#pragma unroll
        for (int nt = 0; nt < 4; ++nt)
          acc[mt][nt] = __builtin_amdgcn_mfma_f32_16x16x32_bf16(af[mt], bf[nt],
                                                                acc[mt][nt], 0, 0, 0);
    }
    __syncthreads();   // protect Bs before next kk's rebuild
  }

  // epilogue: D row = q*4+r, col = ml (m91-verified), + bias
  size_t obase = ((size_t)n * COUT) * HW + ((size_t)ho << 6);
#pragma unroll
  for (int mt = 0; mt < 2; ++mt) {
#pragma unroll
    for (int r = 0; r < 4; ++r) {
      int co = (w << 5) + (mt << 4) + (q << 2) + r;
      float bv = bias[co];
#pragma unroll
      for (int nt = 0; nt < 4; ++nt) {
        int wo = (nt << 4) + ml;
        out[obase + (size_t)co * HW + wo] = acc[mt][nt][r] + bv;
      }
    }
  }
}

extern "C" void kernel_launch(void* const* d_in, const int* in_sizes, int n_in,
                              void* d_out, int out_size, void* d_ws, size_t ws_size,
                              hipStream_t stream) {
  const float* x      = (const float*)d_in[0];
  const float* offset = (const float*)d_in[1];
  const float* mask   = (const float*)d_in[2];
  const float* weight = (const float*)d_in[3];
  const float* bias   = (const float*)d_in[4];
  float* out = (float*)d_out;

  u16* xT  = (u16*)d_ws;                                      // 16 MB
  u16* W2f = (u16*)((char*)d_ws + (size_t)NB * HW * CIN * 2); // +1.18 MB

  prep_x<<<512, 256, 0, stream>>>(x, (u32*)xT);
  prep_w<<<288, 256, 0, stream>>>(weight, W2f);
  dcn_main<<<512, 512, 0, stream>>>(offset, mask, bias, xT, W2f, out);
}

// Round 5
// 150.877 us; speedup vs baseline: 1.3342x; 1.0158x over previous
//
#include <hip/hip_runtime.h>
#include <stdint.h>

typedef unsigned int u32;
typedef unsigned short u16;
typedef float f32x4 __attribute__((ext_vector_type(4)));
typedef __fp16 h16x2 __attribute__((ext_vector_type(2)));   // cvt_pkrtz native type
typedef _Float16 f16x8 __attribute__((ext_vector_type(8)));

#define NB   8
#define CIN  256
#define HH   64
#define WW   64
#define HW   4096
#define COUT 256

__device__ __forceinline__ u32 pkh(float lo, float hi) {
  h16x2 h = __builtin_amdgcn_cvt_pkrtz(lo, hi);   // v_cvt_pkrtz_f16_f32, 1 instr
  return __builtin_bit_cast(u32, h);
}
union HU { u32 u; h16x2 h; };

// ---- prep_w: W2f (fp16) in MFMA A-fragment order ----
// frag idx = ((kk*8+cc)*16 + tile)*64 + lane, 8 f16 each.
// co = (tile>>2)*64 + (tile&3)*16 + (lane&15); c = cc*32 + (lane>>4)*8 + j.
__global__ __launch_bounds__(256) void prep_w(const float* __restrict__ w,
                                              u16* __restrict__ W2f) {
  int t = blockIdx.x * 256 + threadIdx.x;   // 73728 total (288 blocks)
  int lane = t & 63;
  int tile = (t >> 6) & 15;
  int cc = (t >> 10) & 7;
  int kk = t >> 13;                          // 0..8
  int co = ((tile >> 2) << 6) + ((tile & 3) << 4) + (lane & 15);
  int c0 = (cc << 5) + ((lane >> 4) << 3);
  u32 pk[4];
#pragma unroll
  for (int jj = 0; jj < 4; ++jj) {
    float v0 = w[((size_t)co * CIN + c0 + 2 * jj) * 9 + kk];
    float v1 = w[((size_t)co * CIN + c0 + 2 * jj + 1) * 9 + kk];
    pk[jj] = pkh(v0, v1);
  }
  *(uint4*)(W2f + (size_t)t * 8) = *(uint4*)pk;
}

// ---- prep_x: xT[n][hw][c] fp16 from x[n][c][hw] fp32 ----
__global__ __launch_bounds__(256) void prep_x(const float* __restrict__ x,
                                              u32* __restrict__ xT) {
  __shared__ u32 tile[64][129];
  int b = blockIdx.x;
  int n = b >> 6;
  int hw0 = (b & 63) << 6;
  int t = threadIdx.x;
  int hw = t & 63;
  const float* xb = x + (size_t)n * CIN * HW + hw0 + hw;
  int cbase = (t >> 6) * 2;
  for (int citer = 0; citer < 32; ++citer) {
    int c = (citer << 3) + cbase;
    float v0 = xb[(size_t)c * HW];
    float v1 = xb[(size_t)(c + 1) * HW];
    tile[hw][c >> 1] = pkh(v0, v1);
  }
  __syncthreads();
  u32* outp = xT + ((size_t)(n * HW + hw0)) * 128;
  int cp = t & 127;
  int hb = t >> 7;
  for (int it = 0; it < 32; ++it) {
    int hwl = (it << 1) + hb;
    outp[(size_t)hwl * 128 + cp] = tile[hwl][cp];
  }
}

// ---- main fused kernel: 512 threads (8 waves), one block per (n, ho) ----
#define BSTRIDE 264   // u16 per Bs row (256 + 8 pad; 528B, keeps b128 at 8-phase floor)

__global__ __launch_bounds__(512, 4) void dcn_main(
    const float* __restrict__ offset, const float* __restrict__ mask,
    const float* __restrict__ bias, const u16* __restrict__ xT,
    const u16* __restrict__ W2f, float* __restrict__ out) {
  __shared__ __align__(16) u16 Bs[64 * BSTRIDE];  // full-tap B tile: 64px x 256ch
  __shared__ __align__(16) float4 swl[576];       // (kk,p): 4 corner wts (mask folded)
  __shared__ __align__(8)  ushort4 sol[576];      // (kk,p): 4 corner position indices

  int bid = blockIdx.x;      // 512 blocks
  int n = bid & 7;           // XCD swizzle: XCD k serves n==k -> 2MB xT slice in L2
  int ho = bid >> 3;
  int t = threadIdx.x;
  int lane = t & 63;
  int w = t >> 6;            // wave 0..7

  // 1) sample precompute: 9 taps x 64 px
  for (int i = t; i < 576; i += 512) {
    int kk = i >> 6, p = i & 63;
    int ky = kk / 3, kx = kk - ky * 3;
    int sp = (ho << 6) + p;
    float dy = offset[(((size_t)n * 18 + kk * 2 + 0) << 12) + sp];
    float dx = offset[(((size_t)n * 18 + kk * 2 + 1) << 12) + sp];
    float m  = mask  [(((size_t)n * 9  + kk) << 12) + sp];
    float ys = (float)(ky + ho - 1) + dy;
    float xs = (float)(kx + p  - 1) + dx;
    float y0f = floorf(ys), x0f = floorf(xs);
    float fy = ys - y0f, fx = xs - x0f;
    int y0 = (int)y0f, x0 = (int)x0f;
    int y1 = y0 + 1, x1 = x0 + 1;
    float vy0 = (y0 >= 0 && y0 < HH) ? 1.f : 0.f;
    float vy1 = (y1 >= 0 && y1 < HH) ? 1.f : 0.f;
    float vx0 = (x0 >= 0 && x0 < WW) ? 1.f : 0.f;
    float vx1 = (x1 >= 0 && x1 < WW) ? 1.f : 0.f;
    float4 wv;
    wv.x = (1.f - fy) * (1.f - fx) * m * vy0 * vx0;
    wv.y = (1.f - fy) * fx * m * vy0 * vx1;
    wv.z = fy * (1.f - fx) * m * vy1 * vx0;
    wv.w = fy * fx * m * vy1 * vx1;
    int iy0 = min(max(y0, 0), HH - 1), iy1 = min(max(y1, 0), HH - 1);
    int ix0 = min(max(x0, 0), WW - 1), ix1 = min(max(x1, 0), WW - 1);
    ushort4 pv;
    pv.x = (u16)((iy0 << 6) + ix0);
    pv.y = (u16)((iy0 << 6) + ix1);
    pv.z = (u16)((iy1 << 6) + ix0);
    pv.w = (u16)((iy1 << 6) + ix1);
    swl[i] = wv;
    sol[i] = pv;
  }
  __syncthreads();

  f32x4 acc[2][4];
#pragma unroll
  for (int a = 0; a < 2; ++a)
#pragma unroll
    for (int b2 = 0; b2 < 4; ++b2) acc[a][b2] = {0.f, 0.f, 0.f, 0.f};

  const char* xTn = (const char*)xT + ((size_t)n * HW << 9);
  int ml = lane & 15, q = lane >> 4;
  int hwid = t >> 5;     // half-wave id 0..15
  int l32 = t & 31;
  int tile0 = ((w >> 1) << 2) + ((w & 1) << 1);   // A-tile index of mt=0 (co0 = w*32)

// one corner: 32-lane coalesced 512B gather + 8 v_fma_mix_f32 (f16 src folded)
#define CORNER(P, WT) do {                                             \
    uint4 qv = *(const uint4*)(bch + ((int)(P) << 9));                 \
    float wt = (WT);                                                   \
    HU h0, h1, h2, h3;                                                 \
    h0.u = qv.x; h1.u = qv.y; h2.u = qv.z; h3.u = qv.w;                \
    s0 = __builtin_fmaf((float)h0.h.x, wt, s0);                        \
    s1 = __builtin_fmaf((float)h0.h.y, wt, s1);                        \
    s2 = __builtin_fmaf((float)h1.h.x, wt, s2);                        \
    s3 = __builtin_fmaf((float)h1.h.y, wt, s3);                        \
    s4 = __builtin_fmaf((float)h2.h.x, wt, s4);                        \
    s5 = __builtin_fmaf((float)h2.h.y, wt, s5);                        \
    s6 = __builtin_fmaf((float)h3.h.x, wt, s6);                        \
    s7 = __builtin_fmaf((float)h3.h.y, wt, s7);                        \
  } while (0)

  for (int kk = 0; kk < 9; ++kk) {
    // -- build full-tap Bs: half-wave covers one pixel's 256 channels --
    // full unroll: 16 independent L2 gathers in flight across the 4 px-iters
#pragma unroll
    for (int i = 0; i < 4; ++i) {
      int px = (i << 4) + hwid;
      const float4 wv = swl[(kk << 6) + px];
      const ushort4 pv = sol[(kk << 6) + px];
      const char* bch = xTn + (l32 << 4);
      float s0=0.f,s1=0.f,s2=0.f,s3=0.f,s4=0.f,s5=0.f,s6=0.f,s7=0.f;
      CORNER(pv.x, wv.x);
      CORNER(pv.y, wv.y);
      CORNER(pv.z, wv.z);
      CORNER(pv.w, wv.w);
      uint4 pkd;
      pkd.x = pkh(s0, s1); pkd.y = pkh(s2, s3);
      pkd.z = pkh(s4, s5); pkd.w = pkh(s6, s7);
      *(uint4*)((char*)Bs + px * (BSTRIDE * 2) + (l32 << 4)) = pkd;
    }
    __syncthreads();

    // -- MFMA over 8 chunks of K=32; NO barriers inside --
#pragma unroll 2
    for (int cc = 0; cc < 8; ++cc) {
      f16x8 af[2], bf[4];
      const u16* abase = W2f + (((size_t)(kk * 8 + cc) << 4) << 6 << 3);
#pragma unroll
      for (int mt = 0; mt < 2; ++mt)
        af[mt] = *(const f16x8*)(abase + ((((tile0 + mt) << 6) + lane) << 3));
#pragma unroll
      for (int nt = 0; nt < 4; ++nt)
        bf[nt] = *(const f16x8*)((const char*)Bs +
                 ((nt << 4) + ml) * (BSTRIDE * 2) + (cc << 6) + (q << 4));
#pragma unroll
      for (int mt = 0; mt < 2; ++mt)
#pragma unroll
        for (int nt = 0; nt < 4; ++nt)
          acc[mt][nt] = __builtin_amdgcn_mfma_f32_16x16x32_f16(af[mt], bf[nt],
                                                               acc[mt][nt], 0, 0, 0);
    }
    __syncthreads();   // protect Bs before next kk's rebuild
  }

  // epilogue: D row = q*4+r, col = ml (m91-verified), + bias
  size_t obase = ((size_t)n * COUT) * HW + ((size_t)ho << 6);
#pragma unroll
  for (int mt = 0; mt < 2; ++mt) {
#pragma unroll
    for (int r = 0; r < 4; ++r) {
      int co = (w << 5) + (mt << 4) + (q << 2) + r;
      float bv = bias[co];
#pragma unroll
      for (int nt = 0; nt < 4; ++nt) {
        int wo = (nt << 4) + ml;
        out[obase + (size_t)co * HW + wo] = acc[mt][nt][r] + bv;
      }
    }
  }
}

extern "C" void kernel_launch(void* const* d_in, const int* in_sizes, int n_in,
                              void* d_out, int out_size, void* d_ws, size_t ws_size,
                              hipStream_t stream) {
  const float* x      = (const float*)d_in[0];
  const float* offset = (const float*)d_in[1];
  const float* mask   = (const float*)d_in[2];
  const float* weight = (const float*)d_in[3];
  const float* bias   = (const float*)d_in[4];
  float* out = (float*)d_out;

  u16* xT  = (u16*)d_ws;                                      // 16 MB fp16
  u16* W2f = (u16*)((char*)d_ws + (size_t)NB * HW * CIN * 2); // +1.18 MB fp16

  prep_x<<<512, 256, 0, stream>>>(x, (u32*)xT);
  prep_w<<<288, 256, 0, stream>>>(weight, W2f);
  dcn_main<<<512, 512, 0, stream>>>(offset, mask, bias, xT, W2f, out);
}

// Round 6
// 148.800 us; speedup vs baseline: 1.3528x; 1.0140x over previous
//
#include <hip/hip_runtime.h>
#include <stdint.h>

typedef unsigned int u32;
typedef unsigned short u16;
typedef float f32x4 __attribute__((ext_vector_type(4)));
typedef __fp16 h16x2 __attribute__((ext_vector_type(2)));   // cvt_pkrtz native type
typedef _Float16 f16x8 __attribute__((ext_vector_type(8)));
typedef float f4u __attribute__((ext_vector_type(4), aligned(4)));  // 4B-aligned vec load

#define NB   8
#define CIN  256
#define HH   64
#define WW   64
#define HW   4096
#define COUT 256
#define BSTR 264   // u16 per Bs row (256 + 8 pad; 528B = 33*16B, keeps b128 aligned)

__device__ __forceinline__ u32 pkh(float lo, float hi) {
  h16x2 h = __builtin_amdgcn_cvt_pkrtz(lo, hi);   // v_cvt_pkrtz_f16_f32, 1 instr
  return __builtin_bit_cast(u32, h);
}
union HU { u32 u; h16x2 h; };

// ---- prep_all: blocks 0..511 transpose x -> xT (fp16 NHWC); 512..639 weights ----
// W2f frag layout: frag = (kk*8+cc)*16 + tile; element: lane*8+j ;
// co = (tile>>2)*64 + (tile&3)*16 + (lane&15); c = cc*32 + (lane>>4)*8 + j.
__global__ __launch_bounds__(256) void prep_all(const float* __restrict__ x,
                                                const float* __restrict__ wgt,
                                                u32* __restrict__ xT,
                                                u32* __restrict__ W2f32) {
  int b = blockIdx.x;
  int t = threadIdx.x;
  if (b < 512) {
    __shared__ u32 tile[64][129];
    int n = b >> 6, hw0 = (b & 63) << 6;
    int hw4 = (t & 15) << 2;
    int cp0 = t >> 4;
    const float* xb = x + (size_t)n * CIN * HW + hw0 + hw4;
#pragma unroll
    for (int it = 0; it < 8; ++it) {
      int cp = (it << 4) + cp0;
      int c = cp << 1;
      f4u v0 = *(const f4u*)(xb + (size_t)c * HW);
      f4u v1 = *(const f4u*)(xb + (size_t)(c + 1) * HW);
      tile[hw4 + 0][cp] = pkh(v0.x, v1.x);
      tile[hw4 + 1][cp] = pkh(v0.y, v1.y);
      tile[hw4 + 2][cp] = pkh(v0.z, v1.z);
      tile[hw4 + 3][cp] = pkh(v0.w, v1.w);
    }
    __syncthreads();
    u32* outp = xT + ((size_t)(n * HW + hw0)) * 128;
    int cp = t & 127, hb = t >> 7;
#pragma unroll
    for (int it = 0; it < 32; ++it) {
      int hwl = (it << 1) + hb;
      outp[(size_t)hwl * 128 + cp] = tile[hwl][cp];
    }
  } else {
    // weights: thread = (co, c-pair); reads 18 consecutive floats
    int tt = (b - 512) * 256 + t;   // 32768 total
    int cp = tt & 127, co = tt >> 7;
    int c = cp << 1;
    const float* p = wgt + ((size_t)co * CIN + c) * 9;
    f4u q0 = *(const f4u*)(p + 0);
    f4u q1 = *(const f4u*)(p + 4);
    f4u q2 = *(const f4u*)(p + 8);
    f4u q3 = *(const f4u*)(p + 12);
    float e16 = p[16], e17 = p[17];
    float a0[9], a1[9];
    a0[0]=q0.x; a0[1]=q0.y; a0[2]=q0.z; a0[3]=q0.w;
    a0[4]=q1.x; a0[5]=q1.y; a0[6]=q1.z; a0[7]=q1.w; a0[8]=q2.x;
    a1[0]=q2.y; a1[1]=q2.z; a1[2]=q2.w;
    a1[3]=q3.x; a1[4]=q3.y; a1[5]=q3.z; a1[6]=q3.w; a1[7]=e16; a1[8]=e17;
    int cc = c >> 5;
    int j = (c >> 1) & 3;
    int lane = (co & 15) | (((c >> 3) & 3) << 4);
    int tile_ = ((co >> 6) << 2) | ((co >> 4) & 3);
#pragma unroll
    for (int kk = 0; kk < 9; ++kk) {
      int frag = (kk * 8 + cc) * 16 + tile_;
      W2f32[(size_t)frag * 256 + lane * 4 + j] = pkh(a0[kk], a1[kk]);
    }
  }
}

// ---- main fused kernel: 512 threads (8 waves), one block per (n, ho) ----
// Double-buffered Bs: build(kk+1) interleaved under MFMA(kk), barriers 18 -> 10.
__global__ __launch_bounds__(512, 4) void dcn_main(
    const float* __restrict__ offset, const float* __restrict__ mask,
    const float* __restrict__ bias, const u16* __restrict__ xT,
    const u16* __restrict__ W2f, float* __restrict__ out) {
  __shared__ __align__(16) u16 Bs[2][64 * BSTR];  // 2 x 33.8 KB
  __shared__ __align__(8)  uint2 swl[576];        // (kk,p): 4 corner wts, fp16 pairs
  __shared__ __align__(8)  ushort4 sol[576];      // (kk,p): 4 corner position indices

  int bid = blockIdx.x;      // 512 blocks
  int n = bid & 7;           // XCD swizzle: XCD k serves n==k -> 2MB xT slice in L2
  int ho = bid >> 3;
  int t = threadIdx.x;
  int lane = t & 63;
  int w = t >> 6;            // wave 0..7

  // 1) sample precompute: 9 taps x 64 px
  for (int i = t; i < 576; i += 512) {
    int kk = i >> 6, p = i & 63;
    int ky = kk / 3, kx = kk - ky * 3;
    int sp = (ho << 6) + p;
    float dy = offset[(((size_t)n * 18 + kk * 2 + 0) << 12) + sp];
    float dx = offset[(((size_t)n * 18 + kk * 2 + 1) << 12) + sp];
    float m  = mask  [(((size_t)n * 9  + kk) << 12) + sp];
    float ys = (float)(ky + ho - 1) + dy;
    float xs = (float)(kx + p  - 1) + dx;
    float y0f = floorf(ys), x0f = floorf(xs);
    float fy = ys - y0f, fx = xs - x0f;
    int y0 = (int)y0f, x0 = (int)x0f;
    int y1 = y0 + 1, x1 = x0 + 1;
    float vy0 = (y0 >= 0 && y0 < HH) ? 1.f : 0.f;
    float vy1 = (y1 >= 0 && y1 < HH) ? 1.f : 0.f;
    float vx0 = (x0 >= 0 && x0 < WW) ? 1.f : 0.f;
    float vx1 = (x1 >= 0 && x1 < WW) ? 1.f : 0.f;
    float w0 = (1.f - fy) * (1.f - fx) * m * vy0 * vx0;
    float w1 = (1.f - fy) * fx * m * vy0 * vx1;
    float w2 = fy * (1.f - fx) * m * vy1 * vx0;
    float w3 = fy * fx * m * vy1 * vx1;
    int iy0 = min(max(y0, 0), HH - 1), iy1 = min(max(y1, 0), HH - 1);
    int ix0 = min(max(x0, 0), WW - 1), ix1 = min(max(x1, 0), WW - 1);
    ushort4 pv;
    pv.x = (u16)((iy0 << 6) + ix0);
    pv.y = (u16)((iy0 << 6) + ix1);
    pv.z = (u16)((iy1 << 6) + ix0);
    pv.w = (u16)((iy1 << 6) + ix1);
    swl[i] = make_uint2(pkh(w0, w1), pkh(w2, w3));
    sol[i] = pv;
  }
  __syncthreads();

  f32x4 acc[2][4];
#pragma unroll
  for (int a = 0; a < 2; ++a)
#pragma unroll
    for (int b2 = 0; b2 < 4; ++b2) acc[a][b2] = {0.f, 0.f, 0.f, 0.f};

  const char* xTn = (const char*)xT + ((size_t)n * HW << 9);
  int ml = lane & 15, q = lane >> 4;
  int hwid = t >> 5;     // half-wave id 0..15
  int l32 = t & 31;
  int tile0 = ((w >> 1) << 2) + ((w & 1) << 1);   // A-tile index of mt=0 (co0 = w*32)
  const char* bch = xTn + (l32 << 4);

// one corner: 32-lane coalesced 512B gather + 8 v_fma_mix_f32 (f16 src folded)
#define CORNER(P, WT) do {                                             \
    uint4 qv = *(const uint4*)(bch + ((int)(P) << 9));                 \
    float wt = (WT);                                                   \
    HU h0, h1, h2, h3;                                                 \
    h0.u = qv.x; h1.u = qv.y; h2.u = qv.z; h3.u = qv.w;                \
    s0 = __builtin_fmaf((float)h0.h.x, wt, s0);                        \
    s1 = __builtin_fmaf((float)h0.h.y, wt, s1);                        \
    s2 = __builtin_fmaf((float)h1.h.x, wt, s2);                        \
    s3 = __builtin_fmaf((float)h1.h.y, wt, s3);                        \
    s4 = __builtin_fmaf((float)h2.h.x, wt, s4);                        \
    s5 = __builtin_fmaf((float)h2.h.y, wt, s5);                        \
    s6 = __builtin_fmaf((float)h3.h.x, wt, s6);                        \
    s7 = __builtin_fmaf((float)h3.h.y, wt, s7);                        \
  } while (0)

  // build one px-iter of tap kk into Bs[buf]; half-wave = one pixel's 256 ch
  auto build = [&](int kk, int i, int buf) {
    int px = (i << 4) + hwid;
    uint2 wu = swl[(kk << 6) + px];
    ushort4 pv = sol[(kk << 6) + px];
    HU ha, hb; ha.u = wu.x; hb.u = wu.y;
    float w0 = (float)ha.h.x, w1 = (float)ha.h.y;
    float w2 = (float)hb.h.x, w3 = (float)hb.h.y;
    float s0=0.f,s1=0.f,s2=0.f,s3=0.f,s4=0.f,s5=0.f,s6=0.f,s7=0.f;
    CORNER(pv.x, w0);
    CORNER(pv.y, w1);
    CORNER(pv.z, w2);
    CORNER(pv.w, w3);
    uint4 pkd;
    pkd.x = pkh(s0, s1); pkd.y = pkh(s2, s3);
    pkd.z = pkh(s4, s5); pkd.w = pkh(s6, s7);
    *(uint4*)((char*)&Bs[buf][0] + px * (BSTR * 2) + (l32 << 4)) = pkd;
  };

  // prologue: build tap 0 into buf 0
#pragma unroll
  for (int i = 0; i < 4; ++i) build(0, i, 0);
  __syncthreads();

#pragma unroll 1
  for (int kk = 0; kk < 9; ++kk) {
    int cur = kk & 1;
#pragma unroll
    for (int g = 0; g < 4; ++g) {
      if (kk < 8) build(kk + 1, g, cur ^ 1);   // gathers overlap the MFMAs below
#pragma unroll
      for (int c2 = 0; c2 < 2; ++c2) {
        int cc = (g << 1) | c2;
        f16x8 af[2], bf[4];
#pragma unroll
        for (int mt = 0; mt < 2; ++mt)
          af[mt] = *(const f16x8*)(W2f +
                   (((size_t)((kk * 8 + cc) * 16 + tile0 + mt)) << 9) + (lane << 3));
#pragma unroll
        for (int nt = 0; nt < 4; ++nt)
          bf[nt] = *(const f16x8*)((const char*)&Bs[cur][0] +
                   ((nt << 4) + ml) * (BSTR * 2) + (cc << 6) + (q << 4));
#pragma unroll
        for (int mt = 0; mt < 2; ++mt)
#pragma unroll
          for (int nt = 0; nt < 4; ++nt)
            acc[mt][nt] = __builtin_amdgcn_mfma_f32_16x16x32_f16(af[mt], bf[nt],
                                                                 acc[mt][nt], 0, 0, 0);
      }
    }
    __syncthreads();   // build(kk+2) must not overwrite Bs[cur] until MFMA(kk) done
  }

  // epilogue: D row = q*4+r, col = ml (m91-verified), + bias
  size_t obase = ((size_t)n * COUT) * HW + ((size_t)ho << 6);
#pragma unroll
  for (int mt = 0; mt < 2; ++mt) {
#pragma unroll
    for (int r = 0; r < 4; ++r) {
      int co = (w << 5) + (mt << 4) + (q << 2) + r;
      float bv = bias[co];
#pragma unroll
      for (int nt = 0; nt < 4; ++nt) {
        int wo = (nt << 4) + ml;
        out[obase + (size_t)co * HW + wo] = acc[mt][nt][r] + bv;
      }
    }
  }
}

extern "C" void kernel_launch(void* const* d_in, const int* in_sizes, int n_in,
                              void* d_out, int out_size, void* d_ws, size_t ws_size,
                              hipStream_t stream) {
  const float* x      = (const float*)d_in[0];
  const float* offset = (const float*)d_in[1];
  const float* mask   = (const float*)d_in[2];
  const float* weight = (const float*)d_in[3];
  const float* bias   = (const float*)d_in[4];
  float* out = (float*)d_out;

  u16* xT  = (u16*)d_ws;                                      // 16 MB fp16
  u16* W2f = (u16*)((char*)d_ws + (size_t)NB * HW * CIN * 2); // +1.18 MB fp16

  prep_all<<<640, 256, 0, stream>>>(x, weight, (u32*)xT, (u32*)W2f);
  dcn_main<<<512, 512, 0, stream>>>(offset, mask, bias, xT, W2f, out);
}

// Round 7
// 144.601 us; speedup vs baseline: 1.3921x; 1.0290x over previous
//
#include <hip/hip_runtime.h>
#include <stdint.h>

typedef unsigned int u32;
typedef unsigned short u16;
typedef float f32x4 __attribute__((ext_vector_type(4)));
typedef __fp16 h16x2 __attribute__((ext_vector_type(2)));   // cvt_pkrtz native type
typedef _Float16 f16x8 __attribute__((ext_vector_type(8)));
typedef float f4u __attribute__((ext_vector_type(4), aligned(4)));  // 4B-aligned vec load

#define NB   8
#define CIN  256
#define HH   64
#define WW   64
#define HW   4096
#define COUT 256
#define BSTR 264   // u16 per Bs row (256 + 8 pad; 528B = 33*16B -> odd-16B stride)

__device__ __forceinline__ u32 pkh(float lo, float hi) {
  h16x2 h = __builtin_amdgcn_cvt_pkrtz(lo, hi);   // v_cvt_pkrtz_f16_f32, 1 instr
  return __builtin_bit_cast(u32, h);
}
union HU { u32 u; h16x2 h; };

// ---- prep_all: blocks 0..511 transpose x -> xT (fp16 NHWC); 512..639 weights ----
// W2f frag layout: frag = (kk*8+cc)*16 + tile; element: lane*8+j ;
// co = (tile>>2)*64 + (tile&3)*16 + (lane&15); c = cc*32 + (lane>>4)*8 + j.
__global__ __launch_bounds__(256) void prep_all(const float* __restrict__ x,
                                                const float* __restrict__ wgt,
                                                u32* __restrict__ xT,
                                                u32* __restrict__ W2f32) {
  int b = blockIdx.x;
  int t = threadIdx.x;
  if (b < 512) {
    __shared__ u32 tile[64][129];
    int n = b >> 6, hw0 = (b & 63) << 6;
    int hw4 = (t & 15) << 2;
    int cp0 = t >> 4;
    const float* xb = x + (size_t)n * CIN * HW + hw0 + hw4;
#pragma unroll
    for (int it = 0; it < 8; ++it) {
      int cp = (it << 4) + cp0;
      int c = cp << 1;
      f4u v0 = *(const f4u*)(xb + (size_t)c * HW);
      f4u v1 = *(const f4u*)(xb + (size_t)(c + 1) * HW);
      tile[hw4 + 0][cp] = pkh(v0.x, v1.x);
      tile[hw4 + 1][cp] = pkh(v0.y, v1.y);
      tile[hw4 + 2][cp] = pkh(v0.z, v1.z);
      tile[hw4 + 3][cp] = pkh(v0.w, v1.w);
    }
    __syncthreads();
    u32* outp = xT + ((size_t)(n * HW + hw0)) * 128;
    int cp = t & 127, hb = t >> 7;
#pragma unroll
    for (int it = 0; it < 32; ++it) {
      int hwl = (it << 1) + hb;
      outp[(size_t)hwl * 128 + cp] = tile[hwl][cp];
    }
  } else {
    // weights: thread = (co, c-pair); reads 18 consecutive floats
    int tt = (b - 512) * 256 + t;   // 32768 total
    int cp = tt & 127, co = tt >> 7;
    int c = cp << 1;
    const float* p = wgt + ((size_t)co * CIN + c) * 9;
    f4u q0 = *(const f4u*)(p + 0);
    f4u q1 = *(const f4u*)(p + 4);
    f4u q2 = *(const f4u*)(p + 8);
    f4u q3 = *(const f4u*)(p + 12);
    float e16 = p[16], e17 = p[17];
    float a0[9], a1[9];
    a0[0]=q0.x; a0[1]=q0.y; a0[2]=q0.z; a0[3]=q0.w;
    a0[4]=q1.x; a0[5]=q1.y; a0[6]=q1.z; a0[7]=q1.w; a0[8]=q2.x;
    a1[0]=q2.y; a1[1]=q2.z; a1[2]=q2.w;
    a1[3]=q3.x; a1[4]=q3.y; a1[5]=q3.z; a1[6]=q3.w; a1[7]=e16; a1[8]=e17;
    int cc = c >> 5;
    int j = (c >> 1) & 3;
    int lane = (co & 15) | (((c >> 3) & 3) << 4);
    int tile_ = ((co >> 6) << 2) | ((co >> 4) & 3);
#pragma unroll
    for (int kk = 0; kk < 9; ++kk) {
      int frag = (kk * 8 + cc) * 16 + tile_;
      W2f32[(size_t)frag * 256 + lane * 4 + j] = pkh(a0[kk], a1[kk]);
    }
  }
}

// ---- main fused kernel: 512 threads (8 waves), one block per (n, ho) ----
// Register-pipelined: corner gathers issued 2 cc-iters before their combine;
// A-fragments double-buffered in regs one cc ahead. Barriers: 1 per kk.
__global__ __launch_bounds__(512, 4) void dcn_main(
    const float* __restrict__ offset, const float* __restrict__ mask,
    const float* __restrict__ bias, const u16* __restrict__ xT,
    const u16* __restrict__ W2f, float* __restrict__ out) {
  __shared__ __align__(16) u16 Bs[2][64 * BSTR];  // 2 x 33.8 KB
  __shared__ __align__(8)  uint2 swl[576];        // (kk,p): 4 corner wts, fp16 pairs
  __shared__ __align__(8)  ushort4 sol[576];      // (kk,p): 4 corner position indices

  int bid = blockIdx.x;      // 512 blocks
  int n = bid & 7;           // XCD swizzle: XCD k serves n==k -> 2MB xT slice in L2
  int ho = bid >> 3;
  int t = threadIdx.x;
  int lane = t & 63;
  int w = t >> 6;            // wave 0..7

  // 1) sample precompute: 9 taps x 64 px
  for (int i = t; i < 576; i += 512) {
    int kk = i >> 6, p = i & 63;
    int ky = kk / 3, kx = kk - ky * 3;
    int sp = (ho << 6) + p;
    float dy = offset[(((size_t)n * 18 + kk * 2 + 0) << 12) + sp];
    float dx = offset[(((size_t)n * 18 + kk * 2 + 1) << 12) + sp];
    float m  = mask  [(((size_t)n * 9  + kk) << 12) + sp];
    float ys = (float)(ky + ho - 1) + dy;
    float xs = (float)(kx + p  - 1) + dx;
    float y0f = floorf(ys), x0f = floorf(xs);
    float fy = ys - y0f, fx = xs - x0f;
    int y0 = (int)y0f, x0 = (int)x0f;
    int y1 = y0 + 1, x1 = x0 + 1;
    float vy0 = (y0 >= 0 && y0 < HH) ? 1.f : 0.f;
    float vy1 = (y1 >= 0 && y1 < HH) ? 1.f : 0.f;
    float vx0 = (x0 >= 0 && x0 < WW) ? 1.f : 0.f;
    float vx1 = (x1 >= 0 && x1 < WW) ? 1.f : 0.f;
    float w0 = (1.f - fy) * (1.f - fx) * m * vy0 * vx0;
    float w1 = (1.f - fy) * fx * m * vy0 * vx1;
    float w2 = fy * (1.f - fx) * m * vy1 * vx0;
    float w3 = fy * fx * m * vy1 * vx1;
    int iy0 = min(max(y0, 0), HH - 1), iy1 = min(max(y1, 0), HH - 1);
    int ix0 = min(max(x0, 0), WW - 1), ix1 = min(max(x1, 0), WW - 1);
    ushort4 pv;
    pv.x = (u16)((iy0 << 6) + ix0);
    pv.y = (u16)((iy0 << 6) + ix1);
    pv.z = (u16)((iy1 << 6) + ix0);
    pv.w = (u16)((iy1 << 6) + ix1);
    swl[i] = make_uint2(pkh(w0, w1), pkh(w2, w3));
    sol[i] = pv;
  }
  __syncthreads();

  f32x4 acc[2][4];
#pragma unroll
  for (int a = 0; a < 2; ++a)
#pragma unroll
    for (int b2 = 0; b2 < 4; ++b2) acc[a][b2] = {0.f, 0.f, 0.f, 0.f};

  const char* xTn = (const char*)xT + ((size_t)n * HW << 9);
  int ml = lane & 15, q = lane >> 4;
  int hwid = t >> 5;     // half-wave id 0..15
  int l32 = t & 31;
  int tile0 = ((w >> 1) << 2) + ((w & 1) << 1);   // A-tile index of mt=0 (co0 = w*32)
  const char* bch = xTn + (l32 << 4);

// accumulate one register-resident corner (8 v_fma_mix_f32)
#define CMB(G, WT) do {                                                \
    float wt = (WT);                                                   \
    HU h0, h1, h2, h3;                                                 \
    h0.u = (G).x; h1.u = (G).y; h2.u = (G).z; h3.u = (G).w;            \
    s0 = __builtin_fmaf((float)h0.h.x, wt, s0);                        \
    s1 = __builtin_fmaf((float)h0.h.y, wt, s1);                        \
    s2 = __builtin_fmaf((float)h1.h.x, wt, s2);                        \
    s3 = __builtin_fmaf((float)h1.h.y, wt, s3);                        \
    s4 = __builtin_fmaf((float)h2.h.x, wt, s4);                        \
    s5 = __builtin_fmaf((float)h2.h.y, wt, s5);                        \
    s6 = __builtin_fmaf((float)h3.h.x, wt, s6);                        \
    s7 = __builtin_fmaf((float)h3.h.y, wt, s7);                        \
  } while (0)

  // monolithic build for the prologue (tap 0 into buf 0)
  auto build0 = [&](int i) {
    int px = (i << 4) + hwid;
    uint2 wu = swl[px];
    ushort4 pv = sol[px];
    HU ha, hb; ha.u = wu.x; hb.u = wu.y;
    uint4 G0 = *(const uint4*)(bch + ((int)pv.x << 9));
    uint4 G1 = *(const uint4*)(bch + ((int)pv.y << 9));
    uint4 G2 = *(const uint4*)(bch + ((int)pv.z << 9));
    uint4 G3 = *(const uint4*)(bch + ((int)pv.w << 9));
    float s0=0.f,s1=0.f,s2=0.f,s3=0.f,s4=0.f,s5=0.f,s6=0.f,s7=0.f;
    CMB(G0, (float)ha.h.x);
    CMB(G1, (float)ha.h.y);
    CMB(G2, (float)hb.h.x);
    CMB(G3, (float)hb.h.y);
    uint4 pkd;
    pkd.x = pkh(s0, s1); pkd.y = pkh(s2, s3);
    pkd.z = pkh(s4, s5); pkd.w = pkh(s6, s7);
    *(uint4*)((char*)&Bs[0][0] + px * (BSTR * 2) + (l32 << 4)) = pkd;
  };

  // A-fragment loader: flat frag index 0..71
  auto af_load = [&](int fidx, int mt) {
    return *(const f16x8*)(W2f +
           (((size_t)((fidx << 4) + tile0 + mt)) << 9) + (lane << 3));
  };

#pragma unroll
  for (int i = 0; i < 4; ++i) build0(i);
  __syncthreads();

  f16x8 afc0 = af_load(0, 0);
  f16x8 afc1 = af_load(0, 1);

#pragma unroll 1
  for (int kk = 0; kk < 9; ++kk) {
    int cur = kk & 1;
    char* Bw = (char*)&Bs[cur ^ 1][0];
    const char* Br = (const char*)&Bs[cur][0];
    int fbase = kk << 3;
#pragma unroll
    for (int g = 0; g < 4; ++g) {
      int px = (g << 4) + hwid;
      uint4 G0, G1, G2, G3;
      float cw0, cw1, cw2, cw3;
      if (kk < 8) {        // EARLY: issue next-tap gathers for this px-group
        int ii = ((kk + 1) << 6) + px;
        uint2 wu = swl[ii];
        ushort4 pv = sol[ii];
        HU ha, hb; ha.u = wu.x; hb.u = wu.y;
        cw0 = (float)ha.h.x; cw1 = (float)ha.h.y;
        cw2 = (float)hb.h.x; cw3 = (float)hb.h.y;
        G0 = *(const uint4*)(bch + ((int)pv.x << 9));
        G1 = *(const uint4*)(bch + ((int)pv.y << 9));
        G2 = *(const uint4*)(bch + ((int)pv.z << 9));
        G3 = *(const uint4*)(bch + ((int)pv.w << 9));
      }
#pragma unroll
      for (int c2 = 0; c2 < 2; ++c2) {
        int cc = (g << 1) | c2;
        int nf = fbase + cc + 1; if (nf > 71) nf = 71;
        f16x8 afn0 = af_load(nf, 0);     // prefetch A for next cc (or next kk)
        f16x8 afn1 = af_load(nf, 1);
        f16x8 bf[4];
#pragma unroll
        for (int nt = 0; nt < 4; ++nt)
          bf[nt] = *(const f16x8*)(Br + ((nt << 4) + ml) * (BSTR * 2) +
                                   (cc << 6) + (q << 4));
#pragma unroll
        for (int nt = 0; nt < 4; ++nt)
          acc[0][nt] = __builtin_amdgcn_mfma_f32_16x16x32_f16(afc0, bf[nt],
                                                              acc[0][nt], 0, 0, 0);
#pragma unroll
        for (int nt = 0; nt < 4; ++nt)
          acc[1][nt] = __builtin_amdgcn_mfma_f32_16x16x32_f16(afc1, bf[nt],
                                                              acc[1][nt], 0, 0, 0);
        afc0 = afn0; afc1 = afn1;
      }
      if (kk < 8) {        // LATE: combine (vmcnt satisfied) + LDS write
        float s0=0.f,s1=0.f,s2=0.f,s3=0.f,s4=0.f,s5=0.f,s6=0.f,s7=0.f;
        CMB(G0, cw0);
        CMB(G1, cw1);
        CMB(G2, cw2);
        CMB(G3, cw3);
        uint4 pkd;
        pkd.x = pkh(s0, s1); pkd.y = pkh(s2, s3);
        pkd.z = pkh(s4, s5); pkd.w = pkh(s6, s7);
        *(uint4*)(Bw + px * (BSTR * 2) + (l32 << 4)) = pkd;
      }
    }
    __syncthreads();   // all waves done reading Bs[cur] / writing Bs[cur^1]
  }

  // epilogue: D row = q*4+r, col = ml (m91-verified), + bias
  size_t obase = ((size_t)n * COUT) * HW + ((size_t)ho << 6);
#pragma unroll
  for (int mt = 0; mt < 2; ++mt) {
#pragma unroll
    for (int r = 0; r < 4; ++r) {
      int co = (w << 5) + (mt << 4) + (q << 2) + r;
      float bv = bias[co];
#pragma unroll
      for (int nt = 0; nt < 4; ++nt) {
        int wo = (nt << 4) + ml;
        out[obase + (size_t)co * HW + wo] = acc[mt][nt][r] + bv;
      }
    }
  }
}

extern "C" void kernel_launch(void* const* d_in, const int* in_sizes, int n_in,
                              void* d_out, int out_size, void* d_ws, size_t ws_size,
                              hipStream_t stream) {
  const float* x      = (const float*)d_in[0];
  const float* offset = (const float*)d_in[1];
  const float* mask   = (const float*)d_in[2];
  const float* weight = (const float*)d_in[3];
  const float* bias   = (const float*)d_in[4];
  float* out = (float*)d_out;

  u16* xT  = (u16*)d_ws;                                      // 16 MB fp16
  u16* W2f = (u16*)((char*)d_ws + (size_t)NB * HW * CIN * 2); // +1.18 MB fp16

  prep_all<<<640, 256, 0, stream>>>(x, weight, (u32*)xT, (u32*)W2f);
  dcn_main<<<512, 512, 0, stream>>>(offset, mask, bias, xT, W2f, out);
}

// Round 8
// 143.736 us; speedup vs baseline: 1.4005x; 1.0060x over previous
//
#include <hip/hip_runtime.h>
#include <stdint.h>

typedef unsigned int u32;
typedef unsigned short u16;
typedef float f32x4 __attribute__((ext_vector_type(4)));
typedef __fp16 h16x2 __attribute__((ext_vector_type(2)));   // cvt_pkrtz native type
typedef _Float16 f16x8 __attribute__((ext_vector_type(8)));
typedef float f4u __attribute__((ext_vector_type(4), aligned(4)));  // 4B-aligned vec load

#define NB   8
#define CIN  256
#define HH   64
#define WW   64
#define HW   4096
#define COUT 256
#define NPX  128   // pixels per block (2 output rows)
#define BSTR 264   // u16 per Bs row (256 + 8 pad; 528B = 33*16B)

__device__ __forceinline__ u32 pkh(float lo, float hi) {
  h16x2 h = __builtin_amdgcn_cvt_pkrtz(lo, hi);   // v_cvt_pkrtz_f16_f32, 1 instr
  return __builtin_bit_cast(u32, h);
}
union HU { u32 u; h16x2 h; };

// ---- prep_all: blocks 0..511 transpose x -> xT (fp16 NHWC); 512..639 weights ----
// W2f frag layout: frag = (kk*8+cc)*16 + tile; element: lane*8+j ;
// co = (tile>>2)*64 + (tile&3)*16 + (lane&15); c = cc*32 + (lane>>4)*8 + j.
__global__ __launch_bounds__(256) void prep_all(const float* __restrict__ x,
                                                const float* __restrict__ wgt,
                                                u32* __restrict__ xT,
                                                u32* __restrict__ W2f32) {
  int b = blockIdx.x;
  int t = threadIdx.x;
  if (b < 512) {
    __shared__ u32 tile[64][129];
    int n = b >> 6, hw0 = (b & 63) << 6;
    int hw4 = (t & 15) << 2;
    int cp0 = t >> 4;
    const float* xb = x + (size_t)n * CIN * HW + hw0 + hw4;
#pragma unroll
    for (int it = 0; it < 8; ++it) {
      int cp = (it << 4) + cp0;
      int c = cp << 1;
      f4u v0 = *(const f4u*)(xb + (size_t)c * HW);
      f4u v1 = *(const f4u*)(xb + (size_t)(c + 1) * HW);
      tile[hw4 + 0][cp] = pkh(v0.x, v1.x);
      tile[hw4 + 1][cp] = pkh(v0.y, v1.y);
      tile[hw4 + 2][cp] = pkh(v0.z, v1.z);
      tile[hw4 + 3][cp] = pkh(v0.w, v1.w);
    }
    __syncthreads();
    u32* outp = xT + ((size_t)(n * HW + hw0)) * 128;
    int cp = t & 127, hb = t >> 7;
#pragma unroll
    for (int it = 0; it < 32; ++it) {
      int hwl = (it << 1) + hb;
      outp[(size_t)hwl * 128 + cp] = tile[hwl][cp];
    }
  } else {
    // weights: thread = (co, c-pair); reads 18 consecutive floats
    int tt = (b - 512) * 256 + t;   // 32768 total
    int cp = tt & 127, co = tt >> 7;
    int c = cp << 1;
    const float* p = wgt + ((size_t)co * CIN + c) * 9;
    f4u q0 = *(const f4u*)(p + 0);
    f4u q1 = *(const f4u*)(p + 4);
    f4u q2 = *(const f4u*)(p + 8);
    f4u q3 = *(const f4u*)(p + 12);
    float e16 = p[16], e17 = p[17];
    float a0[9], a1[9];
    a0[0]=q0.x; a0[1]=q0.y; a0[2]=q0.z; a0[3]=q0.w;
    a0[4]=q1.x; a0[5]=q1.y; a0[6]=q1.z; a0[7]=q1.w; a0[8]=q2.x;
    a1[0]=q2.y; a1[1]=q2.z; a1[2]=q2.w;
    a1[3]=q3.x; a1[4]=q3.y; a1[5]=q3.z; a1[6]=q3.w; a1[7]=e16; a1[8]=e17;
    int cc = c >> 5;
    int j = (c >> 1) & 3;
    int lane = (co & 15) | (((c >> 3) & 3) << 4);
    int tile_ = ((co >> 6) << 2) | ((co >> 4) & 3);
#pragma unroll
    for (int kk = 0; kk < 9; ++kk) {
      int frag = (kk * 8 + cc) * 16 + tile_;
      W2f32[(size_t)frag * 256 + lane * 4 + j] = pkh(a0[kk], a1[kk]);
    }
  }
}

// ---- main: 256 blocks x 1024 threads; block = 256 Cout x 128 px (2 rows) ----
// 16 waves: strip = w&7 (32 Cout), parity = w>>3 (even/odd K-chunks).
// Dbuf Bs, EARLY-gather/LATE-combine pipeline, epilogue pair-reduce in LDS.
__global__ __launch_bounds__(1024, 4) void dcn_main(
    const float* __restrict__ offset, const float* __restrict__ mask,
    const float* __restrict__ bias, const u16* __restrict__ xT,
    const u16* __restrict__ W2f, float* __restrict__ out) {
  __shared__ __align__(16) u16 Bs[2][NPX * BSTR];  // 2 x 67.6 KB
  __shared__ __align__(8)  uint2 swl[1152];        // (kk,p): 4 corner wts, fp16 pairs
  __shared__ __align__(8)  ushort4 sol[1152];      // (kk,p): 4 corner position indices

  int bid = blockIdx.x;      // 256 blocks = 1/CU
  int n = bid & 7;           // XCD swizzle: XCD k serves n==k -> 2MB xT slice in L2
  int hp = bid >> 3;         // ho-pair 0..31
  int t = threadIdx.x;
  int lane = t & 63;
  int w = t >> 6;            // wave 0..15

  // 1) sample precompute: 9 taps x 128 px
  for (int i = t; i < 1152; i += 1024) {
    int kk = i >> 7, p = i & 127;
    int ky = kk / 3, kx = kk - ky * 3;
    int sp = (hp << 7) + p;             // = ho*64 + (p&63)
    int ho = (hp << 1) + (p >> 6);
    float dy = offset[(((size_t)n * 18 + kk * 2 + 0) << 12) + sp];
    float dx = offset[(((size_t)n * 18 + kk * 2 + 1) << 12) + sp];
    float m  = mask  [(((size_t)n * 9  + kk) << 12) + sp];
    float ys = (float)(ky + ho - 1) + dy;
    float xs = (float)(kx + (p & 63) - 1) + dx;
    float y0f = floorf(ys), x0f = floorf(xs);
    float fy = ys - y0f, fx = xs - x0f;
    int y0 = (int)y0f, x0 = (int)x0f;
    int y1 = y0 + 1, x1 = x0 + 1;
    float vy0 = (y0 >= 0 && y0 < HH) ? 1.f : 0.f;
    float vy1 = (y1 >= 0 && y1 < HH) ? 1.f : 0.f;
    float vx0 = (x0 >= 0 && x0 < WW) ? 1.f : 0.f;
    float vx1 = (x1 >= 0 && x1 < WW) ? 1.f : 0.f;
    float w0 = (1.f - fy) * (1.f - fx) * m * vy0 * vx0;
    float w1 = (1.f - fy) * fx * m * vy0 * vx1;
    float w2 = fy * (1.f - fx) * m * vy1 * vx0;
    float w3 = fy * fx * m * vy1 * vx1;
    int iy0 = min(max(y0, 0), HH - 1), iy1 = min(max(y1, 0), HH - 1);
    int ix0 = min(max(x0, 0), WW - 1), ix1 = min(max(x1, 0), WW - 1);
    ushort4 pv;
    pv.x = (u16)((iy0 << 6) + ix0);
    pv.y = (u16)((iy0 << 6) + ix1);
    pv.z = (u16)((iy1 << 6) + ix0);
    pv.w = (u16)((iy1 << 6) + ix1);
    swl[i] = make_uint2(pkh(w0, w1), pkh(w2, w3));
    sol[i] = pv;
  }
  __syncthreads();

  f32x4 acc[2][8];
#pragma unroll
  for (int a = 0; a < 2; ++a)
#pragma unroll
    for (int b2 = 0; b2 < 8; ++b2) acc[a][b2] = {0.f, 0.f, 0.f, 0.f};

  const char* xTn = (const char*)xT + ((size_t)n * HW << 9);
  int ml = lane & 15, q = lane >> 4;
  int hw32 = t >> 5;     // half-wave id 0..31: builds px = g*32 + hw32
  int l32 = t & 31;
  int strip = w & 7, pr = w >> 3;                     // Cout strip / cc parity
  int tile0 = ((strip >> 1) << 2) + ((strip & 1) << 1);
  const char* bch = xTn + (l32 << 4);

// accumulate one register-resident corner (8 v_fma_mix_f32)
#define CMB(G, WT) do {                                                \
    float wt = (WT);                                                   \
    HU h0, h1, h2, h3;                                                 \
    h0.u = (G).x; h1.u = (G).y; h2.u = (G).z; h3.u = (G).w;            \
    s0 = __builtin_fmaf((float)h0.h.x, wt, s0);                        \
    s1 = __builtin_fmaf((float)h0.h.y, wt, s1);                        \
    s2 = __builtin_fmaf((float)h1.h.x, wt, s2);                        \
    s3 = __builtin_fmaf((float)h1.h.y, wt, s3);                        \
    s4 = __builtin_fmaf((float)h2.h.x, wt, s4);                        \
    s5 = __builtin_fmaf((float)h2.h.y, wt, s5);                        \
    s6 = __builtin_fmaf((float)h3.h.x, wt, s6);                        \
    s7 = __builtin_fmaf((float)h3.h.y, wt, s7);                        \
  } while (0)

  // monolithic build for the prologue (tap 0 into buf 0)
  auto build0 = [&](int g) {
    int px = (g << 5) + hw32;
    uint2 wu = swl[px];
    ushort4 pv = sol[px];
    HU ha, hb; ha.u = wu.x; hb.u = wu.y;
    uint4 G0 = *(const uint4*)(bch + ((int)pv.x << 9));
    uint4 G1 = *(const uint4*)(bch + ((int)pv.y << 9));
    uint4 G2 = *(const uint4*)(bch + ((int)pv.z << 9));
    uint4 G3 = *(const uint4*)(bch + ((int)pv.w << 9));
    float s0=0.f,s1=0.f,s2=0.f,s3=0.f,s4=0.f,s5=0.f,s6=0.f,s7=0.f;
    CMB(G0, (float)ha.h.x);
    CMB(G1, (float)ha.h.y);
    CMB(G2, (float)hb.h.x);
    CMB(G3, (float)hb.h.y);
    uint4 pkd;
    pkd.x = pkh(s0, s1); pkd.y = pkh(s2, s3);
    pkd.z = pkh(s4, s5); pkd.w = pkh(s6, s7);
    *(uint4*)((char*)&Bs[0][0] + px * (BSTR * 2) + (l32 << 4)) = pkd;
  };

  auto af_load = [&](int fidx, int mt) {
    return *(const f16x8*)(W2f + (((size_t)((fidx << 4) + tile0 + mt)) << 9) +
                           (lane << 3));
  };

#pragma unroll
  for (int g = 0; g < 4; ++g) build0(g);
  __syncthreads();

#pragma unroll 1
  for (int kk = 0; kk < 9; ++kk) {
    int cur = kk & 1;
    char* Bw = (char*)&Bs[cur ^ 1][0];
    const char* Br = (const char*)&Bs[cur][0];
    int fbase = kk << 3;
#pragma unroll
    for (int g = 0; g < 4; ++g) {
      int px = (g << 5) + hw32;
      uint4 G0, G1, G2, G3;
      if (kk < 8) {        // EARLY: issue next-tap gathers for this px-group
        ushort4 pv = sol[((kk + 1) << 7) + px];
        G0 = *(const uint4*)(bch + ((int)pv.x << 9));
        G1 = *(const uint4*)(bch + ((int)pv.y << 9));
        G2 = *(const uint4*)(bch + ((int)pv.z << 9));
        G3 = *(const uint4*)(bch + ((int)pv.w << 9));
      }
      // this wave's K-chunk for this g (parity split across waves)
      {
        int cc = (g << 1) | pr;
        f16x8 af0 = af_load(fbase + cc, 0);
        f16x8 af1 = af_load(fbase + cc, 1);
        f16x8 bf[4];
#pragma unroll
        for (int half = 0; half < 2; ++half) {
#pragma unroll
          for (int j = 0; j < 4; ++j)
            bf[j] = *(const f16x8*)(Br +
                    ((((half << 2) + j) << 4) + ml) * (BSTR * 2) +
                    (cc << 6) + (q << 4));
#pragma unroll
          for (int j = 0; j < 4; ++j)
            acc[0][(half << 2) + j] = __builtin_amdgcn_mfma_f32_16x16x32_f16(
                af0, bf[j], acc[0][(half << 2) + j], 0, 0, 0);
#pragma unroll
          for (int j = 0; j < 4; ++j)
            acc[1][(half << 2) + j] = __builtin_amdgcn_mfma_f32_16x16x32_f16(
                af1, bf[j], acc[1][(half << 2) + j], 0, 0, 0);
        }
      }
      if (kk < 8) {        // LATE: combine (vmcnt satisfied) + LDS write
        uint2 wu = swl[((kk + 1) << 7) + px];
        HU ha, hb; ha.u = wu.x; hb.u = wu.y;
        float s0=0.f,s1=0.f,s2=0.f,s3=0.f,s4=0.f,s5=0.f,s6=0.f,s7=0.f;
        CMB(G0, (float)ha.h.x);
        CMB(G1, (float)ha.h.y);
        CMB(G2, (float)hb.h.x);
        CMB(G3, (float)hb.h.y);
        uint4 pkd;
        pkd.x = pkh(s0, s1); pkd.y = pkh(s2, s3);
        pkd.z = pkh(s4, s5); pkd.w = pkh(s6, s7);
        *(uint4*)(Bw + px * (BSTR * 2) + (l32 << 4)) = pkd;
      }
    }
    __syncthreads();   // all waves done reading Bs[cur] / writing Bs[cur^1]
  }

  // epilogue: pair-reduce parity partials through LDS (reuse Bs: 33792 floats)
  float* PS = (float*)&Bs[0][0];
  float* P = PS + strip * 4224 + lane * 66;   // 66-stride: 2-way banks (free)
  if (pr) {
#pragma unroll
    for (int mt = 0; mt < 2; ++mt)
#pragma unroll
      for (int nt = 0; nt < 8; ++nt)
#pragma unroll
        for (int r = 0; r < 4; ++r)
          P[((mt << 3) + nt) * 4 + r] = acc[mt][nt][r];
  }
  __syncthreads();
  if (!pr) {
    // D layout: row = q*4+r, col = ml (m91-verified); px = nt*16+ml
    size_t ob = (size_t)n * COUT * HW + ((size_t)hp << 7);
#pragma unroll
    for (int mt = 0; mt < 2; ++mt) {
#pragma unroll
      for (int r = 0; r < 4; ++r) {
        int co = (strip << 5) + (mt << 4) + (q << 2) + r;
        float bv = bias[co];
#pragma unroll
        for (int nt = 0; nt < 8; ++nt) {
          int px = (nt << 4) + ml;
          out[ob + (size_t)co * HW + px] =
              acc[mt][nt][r] + P[((mt << 3) + nt) * 4 + r] + bv;
        }
      }
    }
  }
}

extern "C" void kernel_launch(void* const* d_in, const int* in_sizes, int n_in,
                              void* d_out, int out_size, void* d_ws, size_t ws_size,
                              hipStream_t stream) {
  const float* x      = (const float*)d_in[0];
  const float* offset = (const float*)d_in[1];
  const float* mask   = (const float*)d_in[2];
  const float* weight = (const float*)d_in[3];
  const float* bias   = (const float*)d_in[4];
  float* out = (float*)d_out;

  u16* xT  = (u16*)d_ws;                                      // 16 MB fp16
  u16* W2f = (u16*)((char*)d_ws + (size_t)NB * HW * CIN * 2); // +1.18 MB fp16

  prep_all<<<640, 256, 0, stream>>>(x, weight, (u32*)xT, (u32*)W2f);
  dcn_main<<<256, 1024, 0, stream>>>(offset, mask, bias, xT, W2f, out);
}